// Round 1
// baseline (889.009 us; speedup 1.0000x reference)
//
#include <hip/hip_runtime.h>

#define Tc 1024
#define Dc 1024
#define Hc 128

typedef __attribute__((ext_vector_type(8))) short bf16x8;
typedef __attribute__((ext_vector_type(4))) float f32x4;
#define MFMA16(A, B, C) __builtin_amdgcn_mfma_f32_16x16x32_bf16(A, B, C, 0, 0, 0)

static __device__ __forceinline__ unsigned asu(float f) { union { float f; unsigned u; } c; c.f = f; return c.u; }
static __device__ __forceinline__ float asf(unsigned u) { union { unsigned u; float f; } c; c.u = u; return c.f; }
static __device__ __forceinline__ ushort bf_rne(float f) {
    unsigned x = asu(f);
    return (ushort)((x + 0x7fffu + ((x >> 16) & 1u)) >> 16);
}
// f ~= hi + lo with ~2^-16 relative accuracy (trunc split; lo captures the remainder)
static __device__ __forceinline__ void split2(float f, ushort& hi, ushort& lo) {
    unsigned u = asu(f);
    hi = (ushort)(u >> 16);
    float r = f - asf(u & 0xffff0000u);
    lo = (ushort)(asu(r) >> 16);
}
static __device__ __forceinline__ float wave_max(float v) {
    #pragma unroll
    for (int o = 32; o > 0; o >>= 1) v = fmaxf(v, __shfl_xor(v, o));
    return v;
}
static __device__ __forceinline__ float wave_sum(float v) {
    #pragma unroll
    for (int o = 32; o > 0; o >>= 1) v += __shfl_xor(v, o);
    return v;
}

// ---------- K0: W [1024,128] f32 -> transposed hi/lo bf16 [sel][128][1024] ----------
__global__ void __launch_bounds__(256) k0_w(
    const float* __restrict__ Wq, const float* __restrict__ Wk, const float* __restrict__ Wv,
    ushort* __restrict__ Wth, ushort* __restrict__ Wtl)
{
    __shared__ float tile[128 * 129];
    const int sel = blockIdx.y;
    const float* W = (sel == 0) ? Wq : (sel == 1) ? Wk : Wv;
    const int d0 = blockIdx.x * 128;
    for (int j = 0; j < 64; ++j) {
        int idx = j * 256 + threadIdx.x;
        int d = idx >> 7, h = idx & 127;
        tile[d * 129 + h] = W[(size_t)(d0 + d) * Hc + h];
    }
    __syncthreads();
    ushort* oh = Wth + (size_t)sel * Hc * Dc;
    ushort* ol = Wtl + (size_t)sel * Hc * Dc;
    for (int j = 0; j < 64; ++j) {
        int idx = j * 256 + threadIdx.x;
        int h = idx >> 7, dl = idx & 127;
        ushort hi, lo; split2(tile[dl * 129 + h], hi, lo);
        oh[(size_t)h * Dc + d0 + dl] = hi;
        ol[(size_t)h * Dc + d0 + dl] = lo;
    }
}

// ---------- K1: fused q/k/v projection, sel split over blockIdx.y (384 blocks).
// grid (128,3) (BM=64), block 256 (4 waves; wave = 16 rows x 128 h)
__global__ void __launch_bounds__(256) k1_qkv(
    const float* __restrict__ x, const ushort* __restrict__ Wth, const ushort* __restrict__ Wtl,
    const float* __restrict__ bq, const float* __restrict__ bk, const float* __restrict__ bv,
    ushort* __restrict__ qh, ushort* __restrict__ ql,
    ushort* __restrict__ kh, ushort* __restrict__ kl,
    ushort* __restrict__ vt)
{
    __shared__ ushort vtile[64 * 130];
    const int m0 = blockIdx.x * 64;
    const int sel = blockIdx.y;
    const int wave = threadIdx.x >> 6, lane = threadIdx.x & 63;
    const int l16 = lane & 15, g = lane >> 4;
    const int b = m0 >> 10, t0 = m0 & 1023;
    const float kscale = 11.313708498984761f;  // sqrt(128)

    const float* xr = x + (size_t)(m0 + wave * 16 + l16) * Dc + g * 8;

    const ushort* wh = Wth + (size_t)sel * Hc * Dc + (size_t)l16 * Dc + g * 8;
    const ushort* wl = Wtl + (size_t)sel * Hc * Dc + (size_t)l16 * Dc + g * 8;
    f32x4 acc[8];
    #pragma unroll
    for (int n = 0; n < 8; ++n) acc[n] = (f32x4){0.f, 0.f, 0.f, 0.f};

    for (int k0 = 0; k0 < Dc; k0 += 32) {
        float4 a0 = *(const float4*)(xr + k0);
        float4 a1 = *(const float4*)(xr + k0 + 4);
        float av[8] = {a0.x, a0.y, a0.z, a0.w, a1.x, a1.y, a1.z, a1.w};
        bf16x8 xh, xl;
        #pragma unroll
        for (int j = 0; j < 8; ++j) {
            ushort h_, l_; split2(av[j], h_, l_);
            xh[j] = (short)h_; xl[j] = (short)l_;
        }
        #pragma unroll
        for (int n = 0; n < 8; ++n) {
            bf16x8 bh = *(const bf16x8*)(wh + (size_t)n * 16 * Dc + k0);
            bf16x8 bl = *(const bf16x8*)(wl + (size_t)n * 16 * Dc + k0);
            acc[n] = MFMA16(xh, bh, acc[n]);
            acc[n] = MFMA16(xl, bh, acc[n]);
            acc[n] = MFMA16(xh, bl, acc[n]);
        }
    }

    const float* bias = (sel == 0) ? bq : (sel == 1) ? bk : bv;
    #pragma unroll
    for (int n = 0; n < 8; ++n) {
        const int h = n * 16 + l16;
        const float bsv = bias[h];
        #pragma unroll
        for (int r = 0; r < 4; ++r) {
            const int mloc = wave * 16 + g * 4 + r;     // 0..63
            const size_t row = (size_t)(m0 + mloc);
            float val = acc[n][r] + bsv;
            if (sel == 0) {
                ushort hi, lo; split2(val, hi, lo);
                qh[row * Hc + h] = hi; ql[row * Hc + h] = lo;
            } else if (sel == 1) {
                val *= kscale;
                ushort hi, lo; split2(val, hi, lo);
                kh[row * Hc + h] = hi; kl[row * Hc + h] = lo;
            } else {
                vtile[mloc * 130 + h] = bf_rne(val);
            }
        }
    }
    if (sel == 2) {
        __syncthreads();
        ushort* vtb = vt + (size_t)b * Hc * Tc;
        for (int j = 0; j < 32; ++j) {
            int idx = j * 256 + threadIdx.x;       // 8192 elems
            int h = idx >> 6, tl = idx & 63;
            vtb[(size_t)h * Tc + t0 + tl] = vtile[tl * 130 + h];
        }
    }
}

// ---------- K2a: S_qk[b,t,v] f32 via 3-product bf16 MFMA (k pre-scaled by sqrt(128)) ----------
// grid (8 t-tiles, 8 v-tiles, 8 b), block 256 (4 waves, 64x64 quadrants)
__global__ void __launch_bounds__(256) k2a_qk(
    const ushort* __restrict__ qh, const ushort* __restrict__ ql,
    const ushort* __restrict__ kh, const ushort* __restrict__ kl,
    float* __restrict__ Sqk)
{
    const int b = blockIdx.z;
    const int t0 = blockIdx.x * 128, v0 = blockIdx.y * 128;
    const int wave = threadIdx.x >> 6, lane = threadIdx.x & 63;
    const int l16 = lane & 15, g = lane >> 4;
    const int mw = (wave & 1) * 64, nw = (wave >> 1) * 64;

    const ushort* qhB = qh + (size_t)(b * Tc + t0 + mw + l16) * Hc + g * 8;
    const ushort* qlB = ql + (size_t)(b * Tc + t0 + mw + l16) * Hc + g * 8;
    const ushort* khB = kh + (size_t)(b * Tc + v0 + nw + l16) * Hc + g * 8;
    const ushort* klB = kl + (size_t)(b * Tc + v0 + nw + l16) * Hc + g * 8;

    f32x4 acc[4][4];
    #pragma unroll
    for (int m = 0; m < 4; ++m)
        #pragma unroll
        for (int n = 0; n < 4; ++n) acc[m][n] = (f32x4){0.f, 0.f, 0.f, 0.f};

    for (int k0 = 0; k0 < Hc; k0 += 32) {
        bf16x8 aH[4], aL[4], bH[4], bL[4];
        #pragma unroll
        for (int i = 0; i < 4; ++i) {
            aH[i] = *(const bf16x8*)(qhB + (size_t)i * 16 * Hc + k0);
            aL[i] = *(const bf16x8*)(qlB + (size_t)i * 16 * Hc + k0);
            bH[i] = *(const bf16x8*)(khB + (size_t)i * 16 * Hc + k0);
            bL[i] = *(const bf16x8*)(klB + (size_t)i * 16 * Hc + k0);
        }
        #pragma unroll
        for (int m = 0; m < 4; ++m)
            #pragma unroll
            for (int n = 0; n < 4; ++n) {
                acc[m][n] = MFMA16(aH[m], bH[n], acc[m][n]);
                acc[m][n] = MFMA16(aH[m], bL[n], acc[m][n]);
                acc[m][n] = MFMA16(aL[m], bH[n], acc[m][n]);
            }
    }
    #pragma unroll
    for (int m = 0; m < 4; ++m)
        #pragma unroll
        for (int n = 0; n < 4; ++n)
            #pragma unroll
            for (int r = 0; r < 4; ++r) {
                int t = t0 + mw + m * 16 + g * 4 + r;
                int v = v0 + nw + n * 16 + l16;
                Sqk[(size_t)(b * Tc + t) * Tc + v] = acc[m][n][r];
            }
}

// ---------- K2b: per-t block: rel f32 -> hi/lo frags -> MFMA (M=b) + Sqk + softmax -> att bf16 ----------
// grid 1024 (t), block 256 (4 waves; wave w owns v in [256w, 256w+256))
// Register double-buffered prefetch of the next vt-tile's rel loads keeps >=8
// global loads in flight per wave (latency-hiding on the 512 MB rel stream).
__global__ void __launch_bounds__(256) k2b_rel_softmax(
    const ushort* __restrict__ qh, const ushort* __restrict__ ql,
    const float* __restrict__ rel, const float* __restrict__ Sqk,
    ushort* __restrict__ att)
{
    __shared__ float Srow[8 * 1024];   // 32 KB
    const int t = blockIdx.x;
    const int wave = threadIdx.x >> 6, lane = threadIdx.x & 63;
    const int l16 = lane & 15, g = lane >> 4;
    const int bq_ = (l16 < 8) ? l16 : 7;   // clamp A rows 8..15 (results unused)

    bf16x8 aH[4], aL[4];
    #pragma unroll
    for (int k = 0; k < 4; ++k) {
        const size_t off = (size_t)(bq_ * Tc + t) * Hc + k * 32 + g * 8;
        aH[k] = *(const bf16x8*)(qh + off);
        aL[k] = *(const bf16x8*)(ql + off);
    }

    // per-lane base: row (wave*256 + l16), col g*8 within rel[t]
    const float* relW = rel + (size_t)t * Tc * Hc + (size_t)(wave * 256 + l16) * Hc + g * 8;

    float4 pa[8], pb[8];   // two vt-tiles in flight (static indices only)

    // compute one vt-tile out of a named register buffer
    auto compute_vt = [&](const float4* buf, int vt) {
        f32x4 acc = (f32x4){0.f, 0.f, 0.f, 0.f};
        #pragma unroll
        for (int kg = 0; kg < 4; ++kg) {
            float rv[8] = {buf[2 * kg].x,     buf[2 * kg].y,     buf[2 * kg].z,     buf[2 * kg].w,
                           buf[2 * kg + 1].x, buf[2 * kg + 1].y, buf[2 * kg + 1].z, buf[2 * kg + 1].w};
            bf16x8 rh, rl;
            #pragma unroll
            for (int j = 0; j < 8; ++j) {
                ushort h_, l_; split2(rv[j], h_, l_);
                rh[j] = (short)h_; rl[j] = (short)l_;
            }
            acc = MFMA16(aH[kg], rh, acc);
            acc = MFMA16(aL[kg], rh, acc);
            acc = MFMA16(aH[kg], rl, acc);
        }
        const int v0 = wave * 256 + vt * 16;
        #pragma unroll
        for (int r = 0; r < 4; ++r) {
            int bb = g * 4 + r;
            if (bb < 8) Srow[bb * 1024 + v0 + l16] = acc[r];
        }
    };

    // prologue: load vt=0 into pa
    #pragma unroll
    for (int kg = 0; kg < 4; ++kg) {
        pa[2 * kg]     = *(const float4*)(relW + kg * 32);
        pa[2 * kg + 1] = *(const float4*)(relW + kg * 32 + 4);
    }

    #pragma unroll
    for (int vt = 0; vt < 16; vt += 2) {
        {   // prefetch vt+1 into pb before consuming pa
            const float* rp = relW + (size_t)(vt + 1) * 16 * Hc;
            #pragma unroll
            for (int kg = 0; kg < 4; ++kg) {
                pb[2 * kg]     = *(const float4*)(rp + kg * 32);
                pb[2 * kg + 1] = *(const float4*)(rp + kg * 32 + 4);
            }
        }
        compute_vt(pa, vt);
        if (vt + 2 < 16) {   // prefetch vt+2 into pa before consuming pb
            const float* rp = relW + (size_t)(vt + 2) * 16 * Hc;
            #pragma unroll
            for (int kg = 0; kg < 4; ++kg) {
                pa[2 * kg]     = *(const float4*)(rp + kg * 32);
                pa[2 * kg + 1] = *(const float4*)(rp + kg * 32 + 4);
            }
        }
        compute_vt(pb, vt + 1);
    }
    __syncthreads();

    for (int rr = 0; rr < 2; ++rr) {
        const int bb = wave * 2 + rr;
        const float* sq = Sqk + (size_t)(bb * Tc + t) * Tc;
        float vals[16];
        float m = -1e30f;
        #pragma unroll
        for (int i = 0; i < 16; ++i) {
            vals[i] = Srow[bb * 1024 + i * 64 + lane] + sq[i * 64 + lane];
            m = fmaxf(m, vals[i]);
        }
        m = wave_max(m);
        float s = 0.f;
        #pragma unroll
        for (int i = 0; i < 16; ++i) { vals[i] = __expf(vals[i] - m); s += vals[i]; }
        s = wave_sum(s);
        const float inv = 1.0f / s;
        ushort* ap = att + (size_t)(bb * Tc + t) * Tc;
        #pragma unroll
        for (int i = 0; i < 16; ++i) ap[i * 64 + lane] = bf_rne(vals[i] * inv);
    }
}

// ---------- K2c: out[b,t,h] f32 = att[b,t,:] @ V[b,:,h]  (Vt layout [b][h][v]) ----------
// grid (32 m-tiles, 8 b), block 128 (2 waves; wave = 16 t-rows x 128 h) -> 256 blocks, full GPU
__global__ void __launch_bounds__(128) k2c_pv(
    const ushort* __restrict__ att, const ushort* __restrict__ vt,
    float* __restrict__ outp)
{
    const int b = blockIdx.y;
    const int wave = threadIdx.x >> 6, lane = threadIdx.x & 63;
    const int l16 = lane & 15, g = lane >> 4;
    const int t0 = blockIdx.x * 32 + wave * 16;

    f32x4 acc[8];
    #pragma unroll
    for (int n = 0; n < 8; ++n) acc[n] = (f32x4){0.f, 0.f, 0.f, 0.f};

    const ushort* attB = att + (size_t)(b * Tc + t0 + l16) * Tc + g * 8;
    const ushort* vtB = vt + (size_t)b * Hc * Tc + (size_t)l16 * Tc + g * 8;

    #pragma unroll 2
    for (int k0 = 0; k0 < Tc; k0 += 32) {
        bf16x8 a = *(const bf16x8*)(attB + k0);
        #pragma unroll
        for (int n = 0; n < 8; ++n) {
            bf16x8 bb = *(const bf16x8*)(vtB + (size_t)n * 16 * Tc + k0);
            acc[n] = MFMA16(a, bb, acc[n]);
        }
    }
    #pragma unroll
    for (int n = 0; n < 8; ++n)
        #pragma unroll
        for (int r = 0; r < 4; ++r) {
            int tt = t0 + g * 4 + r;
            int h = n * 16 + l16;
            outp[(size_t)(b * Tc + tt) * Hc + h] = acc[n][r];
        }
}

extern "C" void kernel_launch(void* const* d_in, const int* in_sizes, int n_in,
                              void* d_out, int out_size, void* d_ws, size_t ws_size,
                              hipStream_t stream) {
    (void)in_sizes; (void)n_in; (void)out_size; (void)ws_size;
    const float* x   = (const float*)d_in[0];
    const float* Wq  = (const float*)d_in[1];
    const float* bq  = (const float*)d_in[2];
    const float* Wk  = (const float*)d_in[3];
    const float* bk  = (const float*)d_in[4];
    const float* Wv  = (const float*)d_in[5];
    const float* bv  = (const float*)d_in[6];
    const float* rel = (const float*)d_in[7];
    float* outp = (float*)d_out;

    char* ws = (char*)d_ws;
    float*  Sqk = (float*) (ws + ((size_t)0  << 20));   // 32 MB
    ushort* att = (ushort*)(ws + ((size_t)32 << 20));   // 16 MB
    ushort* qh  = (ushort*)(ws + ((size_t)48 << 20));   // 2 MB
    ushort* ql  = (ushort*)(ws + ((size_t)50 << 20));   // 2 MB
    ushort* kh  = (ushort*)(ws + ((size_t)52 << 20));   // 2 MB
    ushort* kl  = (ushort*)(ws + ((size_t)54 << 20));   // 2 MB
    ushort* vt  = (ushort*)(ws + ((size_t)56 << 20));   // 2 MB
    ushort* Wth = (ushort*)(ws + ((size_t)58 << 20));   // 0.75 MB
    ushort* Wtl = (ushort*)(ws + ((size_t)59 << 20));   // 0.75 MB

    k0_w<<<dim3(8, 3), 256, 0, stream>>>(Wq, Wk, Wv, Wth, Wtl);
    k1_qkv<<<dim3(128, 3), 256, 0, stream>>>(x, Wth, Wtl, bq, bk, bv, qh, ql, kh, kl, vt);
    k2a_qk<<<dim3(8, 8, 8), 256, 0, stream>>>(qh, ql, kh, kl, Sqk);
    k2b_rel_softmax<<<dim3(1024), 256, 0, stream>>>(qh, ql, rel, Sqk, att);
    k2c_pv<<<dim3(32, 8), 128, 0, stream>>>(att, vt, outp);
}

// Round 2
// 888.372 us; speedup vs baseline: 1.0007x; 1.0007x over previous
//
#include <hip/hip_runtime.h>

#define Tc 1024
#define Dc 1024
#define Hc 128

typedef __attribute__((ext_vector_type(8))) short bf16x8;
typedef __attribute__((ext_vector_type(4))) float f32x4;
#define MFMA16(A, B, C) __builtin_amdgcn_mfma_f32_16x16x32_bf16(A, B, C, 0, 0, 0)

static __device__ __forceinline__ unsigned asu(float f) { union { float f; unsigned u; } c; c.f = f; return c.u; }
static __device__ __forceinline__ float asf(unsigned u) { union { unsigned u; float f; } c; c.u = u; return c.f; }
static __device__ __forceinline__ ushort bf_rne(float f) {
    unsigned x = asu(f);
    return (ushort)((x + 0x7fffu + ((x >> 16) & 1u)) >> 16);
}
// f ~= hi + lo with ~2^-16 relative accuracy (trunc split; lo captures the remainder)
static __device__ __forceinline__ void split2(float f, ushort& hi, ushort& lo) {
    unsigned u = asu(f);
    hi = (ushort)(u >> 16);
    float r = f - asf(u & 0xffff0000u);
    lo = (ushort)(asu(r) >> 16);
}
static __device__ __forceinline__ float wave_max(float v) {
    #pragma unroll
    for (int o = 32; o > 0; o >>= 1) v = fmaxf(v, __shfl_xor(v, o));
    return v;
}
static __device__ __forceinline__ float wave_sum(float v) {
    #pragma unroll
    for (int o = 32; o > 0; o >>= 1) v += __shfl_xor(v, o);
    return v;
}

// ---------- K0: W [1024,128] f32 -> transposed hi/lo bf16 [sel][128][1024] ----------
__global__ void __launch_bounds__(256) k0_w(
    const float* __restrict__ Wq, const float* __restrict__ Wk, const float* __restrict__ Wv,
    ushort* __restrict__ Wth, ushort* __restrict__ Wtl)
{
    __shared__ float tile[128 * 129];
    const int sel = blockIdx.y;
    const float* W = (sel == 0) ? Wq : (sel == 1) ? Wk : Wv;
    const int d0 = blockIdx.x * 128;
    for (int j = 0; j < 64; ++j) {
        int idx = j * 256 + threadIdx.x;
        int d = idx >> 7, h = idx & 127;
        tile[d * 129 + h] = W[(size_t)(d0 + d) * Hc + h];
    }
    __syncthreads();
    ushort* oh = Wth + (size_t)sel * Hc * Dc;
    ushort* ol = Wtl + (size_t)sel * Hc * Dc;
    for (int j = 0; j < 64; ++j) {
        int idx = j * 256 + threadIdx.x;
        int h = idx >> 7, dl = idx & 127;
        ushort hi, lo; split2(tile[dl * 129 + h], hi, lo);
        oh[(size_t)h * Dc + d0 + dl] = hi;
        ol[(size_t)h * Dc + d0 + dl] = lo;
    }
}

// ---------- K1: fused q/k/v projection, sel split over blockIdx.y (384 blocks).
// grid (128,3) (BM=64), block 256 (4 waves; wave = 16 rows x 128 h)
__global__ void __launch_bounds__(256) k1_qkv(
    const float* __restrict__ x, const ushort* __restrict__ Wth, const ushort* __restrict__ Wtl,
    const float* __restrict__ bq, const float* __restrict__ bk, const float* __restrict__ bv,
    ushort* __restrict__ qh, ushort* __restrict__ ql,
    ushort* __restrict__ kh, ushort* __restrict__ kl,
    ushort* __restrict__ vt)
{
    __shared__ ushort vtile[64 * 130];
    const int m0 = blockIdx.x * 64;
    const int sel = blockIdx.y;
    const int wave = threadIdx.x >> 6, lane = threadIdx.x & 63;
    const int l16 = lane & 15, g = lane >> 4;
    const int b = m0 >> 10, t0 = m0 & 1023;
    const float kscale = 11.313708498984761f;  // sqrt(128)

    const float* xr = x + (size_t)(m0 + wave * 16 + l16) * Dc + g * 8;

    const ushort* wh = Wth + (size_t)sel * Hc * Dc + (size_t)l16 * Dc + g * 8;
    const ushort* wl = Wtl + (size_t)sel * Hc * Dc + (size_t)l16 * Dc + g * 8;
    f32x4 acc[8];
    #pragma unroll
    for (int n = 0; n < 8; ++n) acc[n] = (f32x4){0.f, 0.f, 0.f, 0.f};

    for (int k0 = 0; k0 < Dc; k0 += 32) {
        float4 a0 = *(const float4*)(xr + k0);
        float4 a1 = *(const float4*)(xr + k0 + 4);
        float av[8] = {a0.x, a0.y, a0.z, a0.w, a1.x, a1.y, a1.z, a1.w};
        bf16x8 xh, xl;
        #pragma unroll
        for (int j = 0; j < 8; ++j) {
            ushort h_, l_; split2(av[j], h_, l_);
            xh[j] = (short)h_; xl[j] = (short)l_;
        }
        #pragma unroll
        for (int n = 0; n < 8; ++n) {
            bf16x8 bh = *(const bf16x8*)(wh + (size_t)n * 16 * Dc + k0);
            bf16x8 bl = *(const bf16x8*)(wl + (size_t)n * 16 * Dc + k0);
            acc[n] = MFMA16(xh, bh, acc[n]);
            acc[n] = MFMA16(xl, bh, acc[n]);
            acc[n] = MFMA16(xh, bl, acc[n]);
        }
    }

    const float* bias = (sel == 0) ? bq : (sel == 1) ? bk : bv;
    #pragma unroll
    for (int n = 0; n < 8; ++n) {
        const int h = n * 16 + l16;
        const float bsv = bias[h];
        #pragma unroll
        for (int r = 0; r < 4; ++r) {
            const int mloc = wave * 16 + g * 4 + r;     // 0..63
            const size_t row = (size_t)(m0 + mloc);
            float val = acc[n][r] + bsv;
            if (sel == 0) {
                ushort hi, lo; split2(val, hi, lo);
                qh[row * Hc + h] = hi; ql[row * Hc + h] = lo;
            } else if (sel == 1) {
                val *= kscale;
                ushort hi, lo; split2(val, hi, lo);
                kh[row * Hc + h] = hi; kl[row * Hc + h] = lo;
            } else {
                vtile[mloc * 130 + h] = bf_rne(val);
            }
        }
    }
    if (sel == 2) {
        __syncthreads();
        ushort* vtb = vt + (size_t)b * Hc * Tc;
        for (int j = 0; j < 32; ++j) {
            int idx = j * 256 + threadIdx.x;       // 8192 elems
            int h = idx >> 6, tl = idx & 63;
            vtb[(size_t)h * Tc + t0 + tl] = vtile[tl * 130 + h];
        }
    }
}

// ---------- K2a: S_qk[b,t,v] f32 via 3-product bf16 MFMA (k pre-scaled by sqrt(128)) ----------
// grid (8 t-tiles, 8 v-tiles, 8 b), block 256 (4 waves, 64x64 quadrants)
__global__ void __launch_bounds__(256) k2a_qk(
    const ushort* __restrict__ qh, const ushort* __restrict__ ql,
    const ushort* __restrict__ kh, const ushort* __restrict__ kl,
    float* __restrict__ Sqk)
{
    const int b = blockIdx.z;
    const int t0 = blockIdx.x * 128, v0 = blockIdx.y * 128;
    const int wave = threadIdx.x >> 6, lane = threadIdx.x & 63;
    const int l16 = lane & 15, g = lane >> 4;
    const int mw = (wave & 1) * 64, nw = (wave >> 1) * 64;

    const ushort* qhB = qh + (size_t)(b * Tc + t0 + mw + l16) * Hc + g * 8;
    const ushort* qlB = ql + (size_t)(b * Tc + t0 + mw + l16) * Hc + g * 8;
    const ushort* khB = kh + (size_t)(b * Tc + v0 + nw + l16) * Hc + g * 8;
    const ushort* klB = kl + (size_t)(b * Tc + v0 + nw + l16) * Hc + g * 8;

    f32x4 acc[4][4];
    #pragma unroll
    for (int m = 0; m < 4; ++m)
        #pragma unroll
        for (int n = 0; n < 4; ++n) acc[m][n] = (f32x4){0.f, 0.f, 0.f, 0.f};

    for (int k0 = 0; k0 < Hc; k0 += 32) {
        bf16x8 aH[4], aL[4], bH[4], bL[4];
        #pragma unroll
        for (int i = 0; i < 4; ++i) {
            aH[i] = *(const bf16x8*)(qhB + (size_t)i * 16 * Hc + k0);
            aL[i] = *(const bf16x8*)(qlB + (size_t)i * 16 * Hc + k0);
            bH[i] = *(const bf16x8*)(khB + (size_t)i * 16 * Hc + k0);
            bL[i] = *(const bf16x8*)(klB + (size_t)i * 16 * Hc + k0);
        }
        #pragma unroll
        for (int m = 0; m < 4; ++m)
            #pragma unroll
            for (int n = 0; n < 4; ++n) {
                acc[m][n] = MFMA16(aH[m], bH[n], acc[m][n]);
                acc[m][n] = MFMA16(aH[m], bL[n], acc[m][n]);
                acc[m][n] = MFMA16(aL[m], bH[n], acc[m][n]);
            }
    }
    #pragma unroll
    for (int m = 0; m < 4; ++m)
        #pragma unroll
        for (int n = 0; n < 4; ++n)
            #pragma unroll
            for (int r = 0; r < 4; ++r) {
                int t = t0 + mw + m * 16 + g * 4 + r;
                int v = v0 + nw + n * 16 + l16;
                Sqk[(size_t)(b * Tc + t) * Tc + v] = acc[m][n][r];
            }
}

// ---------- K2b: per-t block: rel f32 -> hi/lo frags -> MFMA (M=b) + Sqk + softmax -> att bf16 ----------
// grid 1024 (t), block 256 (4 waves; wave w owns v in [256w, 256w+256))
// 2-deep register double-buffer with FULLY NAMED registers (no arrays, no lambda,
// no address-taking) so nothing can fall to scratch. Identical math to before.
#define K2B_LOAD(P, VT) do {                                                   \
    const float* rp_ = relW + (size_t)(VT) * 16 * Hc;                          \
    P##0 = *(const float4*)(rp_ +  0); P##1 = *(const float4*)(rp_ +  4);      \
    P##2 = *(const float4*)(rp_ + 32); P##3 = *(const float4*)(rp_ + 36);      \
    P##4 = *(const float4*)(rp_ + 64); P##5 = *(const float4*)(rp_ + 68);      \
    P##6 = *(const float4*)(rp_ + 96); P##7 = *(const float4*)(rp_ + 100);     \
} while (0)

#define K2B_CVT1(RH, RL, J, V) { ushort h_, l_; split2((V), h_, l_); RH[J] = (short)h_; RL[J] = (short)l_; }

#define K2B_KG(F0, F1, KG) {                                                   \
    bf16x8 rh_, rl_;                                                           \
    K2B_CVT1(rh_, rl_, 0, F0.x) K2B_CVT1(rh_, rl_, 1, F0.y)                    \
    K2B_CVT1(rh_, rl_, 2, F0.z) K2B_CVT1(rh_, rl_, 3, F0.w)                    \
    K2B_CVT1(rh_, rl_, 4, F1.x) K2B_CVT1(rh_, rl_, 5, F1.y)                    \
    K2B_CVT1(rh_, rl_, 6, F1.z) K2B_CVT1(rh_, rl_, 7, F1.w)                    \
    acc = MFMA16(aH[KG], rh_, acc);                                            \
    acc = MFMA16(aL[KG], rh_, acc);                                            \
    acc = MFMA16(aH[KG], rl_, acc);                                            \
}

#define K2B_COMPUTE(P, VT) {                                                   \
    f32x4 acc = (f32x4){0.f, 0.f, 0.f, 0.f};                                   \
    K2B_KG(P##0, P##1, 0)                                                      \
    K2B_KG(P##2, P##3, 1)                                                      \
    K2B_KG(P##4, P##5, 2)                                                      \
    K2B_KG(P##6, P##7, 3)                                                      \
    const int v0_ = wave * 256 + (VT) * 16;                                    \
    if (g < 2) {                                                               \
        Srow[(g * 4 + 0) * 1024 + v0_ + l16] = acc[0];                         \
        Srow[(g * 4 + 1) * 1024 + v0_ + l16] = acc[1];                         \
        Srow[(g * 4 + 2) * 1024 + v0_ + l16] = acc[2];                         \
        Srow[(g * 4 + 3) * 1024 + v0_ + l16] = acc[3];                         \
    }                                                                          \
}

__global__ void __launch_bounds__(256, 2) k2b_rel_softmax(
    const ushort* __restrict__ qh, const ushort* __restrict__ ql,
    const float* __restrict__ rel, const float* __restrict__ Sqk,
    ushort* __restrict__ att)
{
    __shared__ float Srow[8 * 1024];   // 32 KB
    const int t = blockIdx.x;
    const int wave = threadIdx.x >> 6, lane = threadIdx.x & 63;
    const int l16 = lane & 15, g = lane >> 4;
    const int bq_ = (l16 < 8) ? l16 : 7;   // clamp A rows 8..15 (results unused)

    bf16x8 aH[4], aL[4];
    #pragma unroll
    for (int k = 0; k < 4; ++k) {
        const size_t off = (size_t)(bq_ * Tc + t) * Hc + k * 32 + g * 8;
        aH[k] = *(const bf16x8*)(qh + off);
        aL[k] = *(const bf16x8*)(ql + off);
    }

    // per-lane base: row (wave*256 + l16), col g*8 within rel[t]
    const float* relW = rel + (size_t)t * Tc * Hc + (size_t)(wave * 256 + l16) * Hc + g * 8;

    float4 p0, p1, p2, p3, p4, p5, p6, p7;
    float4 q0, q1, q2, q3, q4, q5, q6, q7;

    K2B_LOAD(p, 0);
    K2B_LOAD(q, 1);

    #pragma unroll
    for (int vt = 0; vt < 16; vt += 2) {
        K2B_COMPUTE(p, vt);
        if (vt + 2 < 16) K2B_LOAD(p, vt + 2);
        K2B_COMPUTE(q, vt + 1);
        if (vt + 3 < 16) K2B_LOAD(q, vt + 3);
    }
    __syncthreads();

    for (int rr = 0; rr < 2; ++rr) {
        const int bb = wave * 2 + rr;
        const float* sq = Sqk + (size_t)(bb * Tc + t) * Tc;
        float vals[16];
        float m = -1e30f;
        #pragma unroll
        for (int i = 0; i < 16; ++i) {
            vals[i] = Srow[bb * 1024 + i * 64 + lane] + sq[i * 64 + lane];
            m = fmaxf(m, vals[i]);
        }
        m = wave_max(m);
        float s = 0.f;
        #pragma unroll
        for (int i = 0; i < 16; ++i) { vals[i] = __expf(vals[i] - m); s += vals[i]; }
        s = wave_sum(s);
        const float inv = 1.0f / s;
        ushort* ap = att + (size_t)(bb * Tc + t) * Tc;
        #pragma unroll
        for (int i = 0; i < 16; ++i) ap[i * 64 + lane] = bf_rne(vals[i] * inv);
    }
}

// ---------- K2c: out[b,t,h] f32 = att[b,t,:] @ V[b,:,h]  (Vt layout [b][h][v]) ----------
// grid (32 m-tiles, 8 b), block 256 (4 waves; wave = 16 t-rows x 64 h) -> 1024 waves, 4/CU
__global__ void __launch_bounds__(256) k2c_pv(
    const ushort* __restrict__ att, const ushort* __restrict__ vt,
    float* __restrict__ outp)
{
    const int b = blockIdx.y;
    const int wave = threadIdx.x >> 6, lane = threadIdx.x & 63;
    const int l16 = lane & 15, g = lane >> 4;
    const int t0 = blockIdx.x * 32 + (wave & 1) * 16;
    const int h0 = (wave >> 1) * 64;

    f32x4 acc[4];
    #pragma unroll
    for (int n = 0; n < 4; ++n) acc[n] = (f32x4){0.f, 0.f, 0.f, 0.f};

    const ushort* attB = att + (size_t)(b * Tc + t0 + l16) * Tc + g * 8;
    const ushort* vtB = vt + (size_t)b * Hc * Tc + (size_t)(h0 + l16) * Tc + g * 8;

    #pragma unroll 2
    for (int k0 = 0; k0 < Tc; k0 += 32) {
        bf16x8 a = *(const bf16x8*)(attB + k0);
        #pragma unroll
        for (int n = 0; n < 4; ++n) {
            bf16x8 bb = *(const bf16x8*)(vtB + (size_t)n * 16 * Tc + k0);
            acc[n] = MFMA16(a, bb, acc[n]);
        }
    }
    #pragma unroll
    for (int n = 0; n < 4; ++n)
        #pragma unroll
        for (int r = 0; r < 4; ++r) {
            int tt = t0 + g * 4 + r;
            int h = h0 + n * 16 + l16;
            outp[(size_t)(b * Tc + tt) * Hc + h] = acc[n][r];
        }
}

extern "C" void kernel_launch(void* const* d_in, const int* in_sizes, int n_in,
                              void* d_out, int out_size, void* d_ws, size_t ws_size,
                              hipStream_t stream) {
    (void)in_sizes; (void)n_in; (void)out_size; (void)ws_size;
    const float* x   = (const float*)d_in[0];
    const float* Wq  = (const float*)d_in[1];
    const float* bq  = (const float*)d_in[2];
    const float* Wk  = (const float*)d_in[3];
    const float* bk  = (const float*)d_in[4];
    const float* Wv  = (const float*)d_in[5];
    const float* bv  = (const float*)d_in[6];
    const float* rel = (const float*)d_in[7];
    float* outp = (float*)d_out;

    char* ws = (char*)d_ws;
    float*  Sqk = (float*) (ws + ((size_t)0  << 20));   // 32 MB
    ushort* att = (ushort*)(ws + ((size_t)32 << 20));   // 16 MB
    ushort* qh  = (ushort*)(ws + ((size_t)48 << 20));   // 2 MB
    ushort* ql  = (ushort*)(ws + ((size_t)50 << 20));   // 2 MB
    ushort* kh  = (ushort*)(ws + ((size_t)52 << 20));   // 2 MB
    ushort* kl  = (ushort*)(ws + ((size_t)54 << 20));   // 2 MB
    ushort* vt  = (ushort*)(ws + ((size_t)56 << 20));   // 2 MB
    ushort* Wth = (ushort*)(ws + ((size_t)58 << 20));   // 0.75 MB
    ushort* Wtl = (ushort*)(ws + ((size_t)59 << 20));   // 0.75 MB

    k0_w<<<dim3(8, 3), 256, 0, stream>>>(Wq, Wk, Wv, Wth, Wtl);
    k1_qkv<<<dim3(128, 3), 256, 0, stream>>>(x, Wth, Wtl, bq, bk, bv, qh, ql, kh, kl, vt);
    k2a_qk<<<dim3(8, 8, 8), 256, 0, stream>>>(qh, ql, kh, kl, Sqk);
    k2b_rel_softmax<<<dim3(1024), 256, 0, stream>>>(qh, ql, rel, Sqk, att);
    k2c_pv<<<dim3(32, 8), 256, 0, stream>>>(att, vt, outp);
}

// Round 3
// 885.227 us; speedup vs baseline: 1.0043x; 1.0036x over previous
//
#include <hip/hip_runtime.h>

#define Tc 1024
#define Dc 1024
#define Hc 128

typedef __attribute__((ext_vector_type(8))) short bf16x8;
typedef __attribute__((ext_vector_type(4))) float f32x4;
typedef __attribute__((ext_vector_type(4))) unsigned u32x4;
#define MFMA16(A, B, C) __builtin_amdgcn_mfma_f32_16x16x32_bf16(A, B, C, 0, 0, 0)

static __device__ __forceinline__ unsigned asu(float f) { union { float f; unsigned u; } c; c.f = f; return c.u; }
static __device__ __forceinline__ float asf(unsigned u) { union { unsigned u; float f; } c; c.u = u; return c.f; }
static __device__ __forceinline__ ushort bf_rne(float f) {
    unsigned x = asu(f);
    return (ushort)((x + 0x7fffu + ((x >> 16) & 1u)) >> 16);
}
// f ~= hi + lo with ~2^-16 relative accuracy (trunc split; lo captures the remainder)
static __device__ __forceinline__ void split2(float f, ushort& hi, ushort& lo) {
    unsigned u = asu(f);
    hi = (ushort)(u >> 16);
    float r = f - asf(u & 0xffff0000u);
    lo = (ushort)(asu(r) >> 16);
}
static __device__ __forceinline__ float wave_max(float v) {
    #pragma unroll
    for (int o = 32; o > 0; o >>= 1) v = fmaxf(v, __shfl_xor(v, o));
    return v;
}
static __device__ __forceinline__ float wave_sum(float v) {
    #pragma unroll
    for (int o = 32; o > 0; o >>= 1) v += __shfl_xor(v, o);
    return v;
}

// ---------- K0: W [1024,128] f32 -> transposed hi/lo bf16 [sel][128][1024] ----------
__global__ void __launch_bounds__(256) k0_w(
    const float* __restrict__ Wq, const float* __restrict__ Wk, const float* __restrict__ Wv,
    ushort* __restrict__ Wth, ushort* __restrict__ Wtl)
{
    __shared__ float tile[128 * 129];
    const int sel = blockIdx.y;
    const float* W = (sel == 0) ? Wq : (sel == 1) ? Wk : Wv;
    const int d0 = blockIdx.x * 128;
    for (int j = 0; j < 64; ++j) {
        int idx = j * 256 + threadIdx.x;
        int d = idx >> 7, h = idx & 127;
        tile[d * 129 + h] = W[(size_t)(d0 + d) * Hc + h];
    }
    __syncthreads();
    ushort* oh = Wth + (size_t)sel * Hc * Dc;
    ushort* ol = Wtl + (size_t)sel * Hc * Dc;
    for (int j = 0; j < 64; ++j) {
        int idx = j * 256 + threadIdx.x;
        int h = idx >> 7, dl = idx & 127;
        ushort hi, lo; split2(tile[dl * 129 + h], hi, lo);
        oh[(size_t)h * Dc + d0 + dl] = hi;
        ol[(size_t)h * Dc + d0 + dl] = lo;
    }
}

// ---------- K1: fused q/k/v projection, sel split over blockIdx.y (384 blocks).
// grid (128,3) (BM=64), block 256 (4 waves; wave = 16 rows x 128 h)
__global__ void __launch_bounds__(256) k1_qkv(
    const float* __restrict__ x, const ushort* __restrict__ Wth, const ushort* __restrict__ Wtl,
    const float* __restrict__ bq, const float* __restrict__ bk, const float* __restrict__ bv,
    ushort* __restrict__ qh, ushort* __restrict__ ql,
    ushort* __restrict__ kh, ushort* __restrict__ kl,
    ushort* __restrict__ vt)
{
    __shared__ ushort vtile[64 * 130];
    const int m0 = blockIdx.x * 64;
    const int sel = blockIdx.y;
    const int wave = threadIdx.x >> 6, lane = threadIdx.x & 63;
    const int l16 = lane & 15, g = lane >> 4;
    const int b = m0 >> 10, t0 = m0 & 1023;
    const float kscale = 11.313708498984761f;  // sqrt(128)

    const float* xr = x + (size_t)(m0 + wave * 16 + l16) * Dc + g * 8;

    const ushort* wh = Wth + (size_t)sel * Hc * Dc + (size_t)l16 * Dc + g * 8;
    const ushort* wl = Wtl + (size_t)sel * Hc * Dc + (size_t)l16 * Dc + g * 8;
    f32x4 acc[8];
    #pragma unroll
    for (int n = 0; n < 8; ++n) acc[n] = (f32x4){0.f, 0.f, 0.f, 0.f};

    for (int k0 = 0; k0 < Dc; k0 += 32) {
        float4 a0 = *(const float4*)(xr + k0);
        float4 a1 = *(const float4*)(xr + k0 + 4);
        float av[8] = {a0.x, a0.y, a0.z, a0.w, a1.x, a1.y, a1.z, a1.w};
        bf16x8 xh, xl;
        #pragma unroll
        for (int j = 0; j < 8; ++j) {
            ushort h_, l_; split2(av[j], h_, l_);
            xh[j] = (short)h_; xl[j] = (short)l_;
        }
        #pragma unroll
        for (int n = 0; n < 8; ++n) {
            bf16x8 bh = *(const bf16x8*)(wh + (size_t)n * 16 * Dc + k0);
            bf16x8 bl = *(const bf16x8*)(wl + (size_t)n * 16 * Dc + k0);
            acc[n] = MFMA16(xh, bh, acc[n]);
            acc[n] = MFMA16(xl, bh, acc[n]);
            acc[n] = MFMA16(xh, bl, acc[n]);
        }
    }

    const float* bias = (sel == 0) ? bq : (sel == 1) ? bk : bv;
    #pragma unroll
    for (int n = 0; n < 8; ++n) {
        const int h = n * 16 + l16;
        const float bsv = bias[h];
        #pragma unroll
        for (int r = 0; r < 4; ++r) {
            const int mloc = wave * 16 + g * 4 + r;     // 0..63
            const size_t row = (size_t)(m0 + mloc);
            float val = acc[n][r] + bsv;
            if (sel == 0) {
                ushort hi, lo; split2(val, hi, lo);
                qh[row * Hc + h] = hi; ql[row * Hc + h] = lo;
            } else if (sel == 1) {
                val *= kscale;
                ushort hi, lo; split2(val, hi, lo);
                kh[row * Hc + h] = hi; kl[row * Hc + h] = lo;
            } else {
                vtile[mloc * 130 + h] = bf_rne(val);
            }
        }
    }
    if (sel == 2) {
        __syncthreads();
        ushort* vtb = vt + (size_t)b * Hc * Tc;
        for (int j = 0; j < 32; ++j) {
            int idx = j * 256 + threadIdx.x;       // 8192 elems
            int h = idx >> 6, tl = idx & 63;
            vtb[(size_t)h * Tc + t0 + tl] = vtile[tl * 130 + h];
        }
    }
}

// ---------- K2a: S_qk[b,t,v] f32 via 3-product bf16 MFMA (k pre-scaled by sqrt(128)) ----------
// grid (8 t-tiles, 8 v-tiles, 8 b), block 256 (4 waves, 64x64 quadrants)
__global__ void __launch_bounds__(256) k2a_qk(
    const ushort* __restrict__ qh, const ushort* __restrict__ ql,
    const ushort* __restrict__ kh, const ushort* __restrict__ kl,
    float* __restrict__ Sqk)
{
    const int b = blockIdx.z;
    const int t0 = blockIdx.x * 128, v0 = blockIdx.y * 128;
    const int wave = threadIdx.x >> 6, lane = threadIdx.x & 63;
    const int l16 = lane & 15, g = lane >> 4;
    const int mw = (wave & 1) * 64, nw = (wave >> 1) * 64;

    const ushort* qhB = qh + (size_t)(b * Tc + t0 + mw + l16) * Hc + g * 8;
    const ushort* qlB = ql + (size_t)(b * Tc + t0 + mw + l16) * Hc + g * 8;
    const ushort* khB = kh + (size_t)(b * Tc + v0 + nw + l16) * Hc + g * 8;
    const ushort* klB = kl + (size_t)(b * Tc + v0 + nw + l16) * Hc + g * 8;

    f32x4 acc[4][4];
    #pragma unroll
    for (int m = 0; m < 4; ++m)
        #pragma unroll
        for (int n = 0; n < 4; ++n) acc[m][n] = (f32x4){0.f, 0.f, 0.f, 0.f};

    for (int k0 = 0; k0 < Hc; k0 += 32) {
        bf16x8 aH[4], aL[4], bH[4], bL[4];
        #pragma unroll
        for (int i = 0; i < 4; ++i) {
            aH[i] = *(const bf16x8*)(qhB + (size_t)i * 16 * Hc + k0);
            aL[i] = *(const bf16x8*)(qlB + (size_t)i * 16 * Hc + k0);
            bH[i] = *(const bf16x8*)(khB + (size_t)i * 16 * Hc + k0);
            bL[i] = *(const bf16x8*)(klB + (size_t)i * 16 * Hc + k0);
        }
        #pragma unroll
        for (int m = 0; m < 4; ++m)
            #pragma unroll
            for (int n = 0; n < 4; ++n) {
                acc[m][n] = MFMA16(aH[m], bH[n], acc[m][n]);
                acc[m][n] = MFMA16(aH[m], bL[n], acc[m][n]);
                acc[m][n] = MFMA16(aL[m], bH[n], acc[m][n]);
            }
    }
    #pragma unroll
    for (int m = 0; m < 4; ++m)
        #pragma unroll
        for (int n = 0; n < 4; ++n)
            #pragma unroll
            for (int r = 0; r < 4; ++r) {
                int t = t0 + mw + m * 16 + g * 4 + r;
                int v = v0 + nw + n * 16 + l16;
                Sqk[(size_t)(b * Tc + t) * Tc + v] = acc[m][n][r];
            }
}

// ---------- K2b: per-t block: rel f32 -> hi/lo frags -> MFMA (M=b) + Sqk + softmax -> att bf16 ----------
// grid 1024 (t), block 256 (4 waves; wave w owns v in [256w, 256w+256))
// 2-deep register double-buffer, pairwise v_perm_b32 hi/lo split (bit-identical
// to split2's truncation, half the VALU ops), Sqk tail rows prefetched at top.
#define K2B_LOAD(P, VT) do {                                                   \
    const float* rp_ = relW + (size_t)(VT) * 16 * Hc;                          \
    P##0 = *(const float4*)(rp_ +  0); P##1 = *(const float4*)(rp_ +  4);      \
    P##2 = *(const float4*)(rp_ + 32); P##3 = *(const float4*)(rp_ + 36);      \
    P##4 = *(const float4*)(rp_ + 64); P##5 = *(const float4*)(rp_ + 68);      \
    P##6 = *(const float4*)(rp_ + 96); P##7 = *(const float4*)(rp_ + 100);     \
} while (0)

// pack hi16(F0),hi16(F1) into UH (low,high) and the truncated remainders into UL
#define K2B_PAIR(UH, UL, F0, F1) {                                             \
    unsigned u0_ = asu(F0), u1_ = asu(F1);                                     \
    UH = __builtin_amdgcn_perm(u1_, u0_, 0x07060302u);                         \
    float r0_ = (F0) - asf(u0_ & 0xffff0000u);                                 \
    float r1_ = (F1) - asf(u1_ & 0xffff0000u);                                 \
    UL = __builtin_amdgcn_perm(asu(r1_), asu(r0_), 0x07060302u);               \
}

#define K2B_KG(F0, F1, KG) {                                                   \
    u32x4 rhu_, rlu_;                                                          \
    K2B_PAIR(rhu_[0], rlu_[0], F0.x, F0.y)                                     \
    K2B_PAIR(rhu_[1], rlu_[1], F0.z, F0.w)                                     \
    K2B_PAIR(rhu_[2], rlu_[2], F1.x, F1.y)                                     \
    K2B_PAIR(rhu_[3], rlu_[3], F1.z, F1.w)                                     \
    bf16x8 rh_ = __builtin_bit_cast(bf16x8, rhu_);                             \
    bf16x8 rl_ = __builtin_bit_cast(bf16x8, rlu_);                             \
    acc = MFMA16(aH[KG], rh_, acc);                                            \
    acc = MFMA16(aL[KG], rh_, acc);                                            \
    acc = MFMA16(aH[KG], rl_, acc);                                            \
}

#define K2B_COMPUTE(P, VT) {                                                   \
    f32x4 acc = (f32x4){0.f, 0.f, 0.f, 0.f};                                   \
    K2B_KG(P##0, P##1, 0)                                                      \
    K2B_KG(P##2, P##3, 1)                                                      \
    K2B_KG(P##4, P##5, 2)                                                      \
    K2B_KG(P##6, P##7, 3)                                                      \
    const int v0_ = wave * 256 + (VT) * 16;                                    \
    if (g < 2) {                                                               \
        Srow[(g * 4 + 0) * 1024 + v0_ + l16] = acc[0];                         \
        Srow[(g * 4 + 1) * 1024 + v0_ + l16] = acc[1];                         \
        Srow[(g * 4 + 2) * 1024 + v0_ + l16] = acc[2];                         \
        Srow[(g * 4 + 3) * 1024 + v0_ + l16] = acc[3];                         \
    }                                                                          \
}

__global__ void __launch_bounds__(256, 2) k2b_rel_softmax(
    const ushort* __restrict__ qh, const ushort* __restrict__ ql,
    const float* __restrict__ rel, const float* __restrict__ Sqk,
    ushort* __restrict__ att)
{
    __shared__ float Srow[8 * 1024];   // 32 KB
    const int t = blockIdx.x;
    const int wave = threadIdx.x >> 6, lane = threadIdx.x & 63;
    const int l16 = lane & 15, g = lane >> 4;
    const int bq_ = (l16 < 8) ? l16 : 7;   // clamp A rows 8..15 (results unused)

    // prefetch the two Sqk tail rows for this wave into registers (issued first,
    // retired long before the tail; hides the tail's HBM latency)
    const float* sq0 = Sqk + (size_t)((wave * 2 + 0) * Tc + t) * Tc;
    const float* sq1 = Sqk + (size_t)((wave * 2 + 1) * Tc + t) * Tc;
    float sqv0[16], sqv1[16];
    #pragma unroll
    for (int i = 0; i < 16; ++i) sqv0[i] = sq0[i * 64 + lane];
    #pragma unroll
    for (int i = 0; i < 16; ++i) sqv1[i] = sq1[i * 64 + lane];

    bf16x8 aH[4], aL[4];
    #pragma unroll
    for (int k = 0; k < 4; ++k) {
        const size_t off = (size_t)(bq_ * Tc + t) * Hc + k * 32 + g * 8;
        aH[k] = *(const bf16x8*)(qh + off);
        aL[k] = *(const bf16x8*)(ql + off);
    }

    // per-lane base: row (wave*256 + l16), col g*8 within rel[t]
    const float* relW = rel + (size_t)t * Tc * Hc + (size_t)(wave * 256 + l16) * Hc + g * 8;

    float4 p0, p1, p2, p3, p4, p5, p6, p7;
    float4 q0, q1, q2, q3, q4, q5, q6, q7;

    K2B_LOAD(p, 0);
    K2B_LOAD(q, 1);

    #pragma unroll
    for (int vt = 0; vt < 16; vt += 2) {
        K2B_COMPUTE(p, vt);
        if (vt + 2 < 16) K2B_LOAD(p, vt + 2);
        K2B_COMPUTE(q, vt + 1);
        if (vt + 3 < 16) K2B_LOAD(q, vt + 3);
    }
    __syncthreads();

    {   // rr = 0
        const int bb = wave * 2 + 0;
        float vals[16];
        float m = -1e30f;
        #pragma unroll
        for (int i = 0; i < 16; ++i) {
            vals[i] = Srow[bb * 1024 + i * 64 + lane] + sqv0[i];
            m = fmaxf(m, vals[i]);
        }
        m = wave_max(m);
        float s = 0.f;
        #pragma unroll
        for (int i = 0; i < 16; ++i) { vals[i] = __expf(vals[i] - m); s += vals[i]; }
        s = wave_sum(s);
        const float inv = 1.0f / s;
        ushort* ap = att + (size_t)(bb * Tc + t) * Tc;
        #pragma unroll
        for (int i = 0; i < 16; ++i) ap[i * 64 + lane] = bf_rne(vals[i] * inv);
    }
    {   // rr = 1
        const int bb = wave * 2 + 1;
        float vals[16];
        float m = -1e30f;
        #pragma unroll
        for (int i = 0; i < 16; ++i) {
            vals[i] = Srow[bb * 1024 + i * 64 + lane] + sqv1[i];
            m = fmaxf(m, vals[i]);
        }
        m = wave_max(m);
        float s = 0.f;
        #pragma unroll
        for (int i = 0; i < 16; ++i) { vals[i] = __expf(vals[i] - m); s += vals[i]; }
        s = wave_sum(s);
        const float inv = 1.0f / s;
        ushort* ap = att + (size_t)(bb * Tc + t) * Tc;
        #pragma unroll
        for (int i = 0; i < 16; ++i) ap[i * 64 + lane] = bf_rne(vals[i] * inv);
    }
}

// ---------- K2c: out[b,t,h] f32 = att[b,t,:] @ V[b,:,h]  (Vt layout [b][h][v]) ----------
// grid (32 m-tiles, 8 b), block 256 (4 waves; wave = 16 t-rows x 64 h)
__global__ void __launch_bounds__(256) k2c_pv(
    const ushort* __restrict__ att, const ushort* __restrict__ vt,
    float* __restrict__ outp)
{
    const int b = blockIdx.y;
    const int wave = threadIdx.x >> 6, lane = threadIdx.x & 63;
    const int l16 = lane & 15, g = lane >> 4;
    const int t0 = blockIdx.x * 32 + (wave & 1) * 16;
    const int h0 = (wave >> 1) * 64;

    f32x4 acc[4];
    #pragma unroll
    for (int n = 0; n < 4; ++n) acc[n] = (f32x4){0.f, 0.f, 0.f, 0.f};

    const ushort* attB = att + (size_t)(b * Tc + t0 + l16) * Tc + g * 8;
    const ushort* vtB = vt + (size_t)b * Hc * Tc + (size_t)(h0 + l16) * Tc + g * 8;

    #pragma unroll 4
    for (int k0 = 0; k0 < Tc; k0 += 32) {
        bf16x8 a = *(const bf16x8*)(attB + k0);
        #pragma unroll
        for (int n = 0; n < 4; ++n) {
            bf16x8 bb = *(const bf16x8*)(vtB + (size_t)n * 16 * Tc + k0);
            acc[n] = MFMA16(a, bb, acc[n]);
        }
    }
    #pragma unroll
    for (int n = 0; n < 4; ++n)
        #pragma unroll
        for (int r = 0; r < 4; ++r) {
            int tt = t0 + g * 4 + r;
            int h = h0 + n * 16 + l16;
            outp[(size_t)(b * Tc + tt) * Hc + h] = acc[n][r];
        }
}

extern "C" void kernel_launch(void* const* d_in, const int* in_sizes, int n_in,
                              void* d_out, int out_size, void* d_ws, size_t ws_size,
                              hipStream_t stream) {
    (void)in_sizes; (void)n_in; (void)out_size; (void)ws_size;
    const float* x   = (const float*)d_in[0];
    const float* Wq  = (const float*)d_in[1];
    const float* bq  = (const float*)d_in[2];
    const float* Wk  = (const float*)d_in[3];
    const float* bk  = (const float*)d_in[4];
    const float* Wv  = (const float*)d_in[5];
    const float* bv  = (const float*)d_in[6];
    const float* rel = (const float*)d_in[7];
    float* outp = (float*)d_out;

    char* ws = (char*)d_ws;
    float*  Sqk = (float*) (ws + ((size_t)0  << 20));   // 32 MB
    ushort* att = (ushort*)(ws + ((size_t)32 << 20));   // 16 MB
    ushort* qh  = (ushort*)(ws + ((size_t)48 << 20));   // 2 MB
    ushort* ql  = (ushort*)(ws + ((size_t)50 << 20));   // 2 MB
    ushort* kh  = (ushort*)(ws + ((size_t)52 << 20));   // 2 MB
    ushort* kl  = (ushort*)(ws + ((size_t)54 << 20));   // 2 MB
    ushort* vt  = (ushort*)(ws + ((size_t)56 << 20));   // 2 MB
    ushort* Wth = (ushort*)(ws + ((size_t)58 << 20));   // 0.75 MB
    ushort* Wtl = (ushort*)(ws + ((size_t)59 << 20));   // 0.75 MB

    k0_w<<<dim3(8, 3), 256, 0, stream>>>(Wq, Wk, Wv, Wth, Wtl);
    k1_qkv<<<dim3(128, 3), 256, 0, stream>>>(x, Wth, Wtl, bq, bk, bv, qh, ql, kh, kl, vt);
    k2a_qk<<<dim3(8, 8, 8), 256, 0, stream>>>(qh, ql, kh, kl, Sqk);
    k2b_rel_softmax<<<dim3(1024), 256, 0, stream>>>(qh, ql, rel, Sqk, att);
    k2c_pv<<<dim3(32, 8), 256, 0, stream>>>(att, vt, outp);
}